// Round 2
// baseline (136.979 us; speedup 1.0000x reference)
//
#include <hip/hip_runtime.h>
#include <math.h>

namespace {

constexpr int NUM_NEG   = 8;
constexpr int BROWS     = 262144;
constexpr int NUM_ITEMS_C = 20000;
constexpr int M_IMP_C   = 2000;
constexpr float MARGIN1 = 0.1f;
constexpr float MARGIN2 = 0.1f;
constexpr float TAU     = 0.2f;
constexpr float EPS1    = 1e-7f;
constexpr float MAXNORM = 1.0f - 1e-5f;

constexpr int RANK_BLOCKS = 2048;
constexpr int CLS_BLOCKS  = 512;
constexpr int CL_BLOCKS   = 64;
constexpr int NPART = RANK_BLOCKS + CLS_BLOCKS + CL_BLOCKS;

__device__ __forceinline__ float wredsum(float v) {
    v += __shfl_xor(v, 1);  v += __shfl_xor(v, 2);  v += __shfl_xor(v, 4);
    v += __shfl_xor(v, 8);  v += __shfl_xor(v, 16); v += __shfl_xor(v, 32);
    return v;
}
__device__ __forceinline__ float wredmax(float v) {
    v = fmaxf(v, __shfl_xor(v, 1));  v = fmaxf(v, __shfl_xor(v, 2));
    v = fmaxf(v, __shfl_xor(v, 4));  v = fmaxf(v, __shfl_xor(v, 8));
    v = fmaxf(v, __shfl_xor(v, 16)); v = fmaxf(v, __shfl_xor(v, 32));
    return v;
}
__device__ __forceinline__ float qredsum(float v) {
    v += __shfl_xor(v, 1); v += __shfl_xor(v, 2);
    v += __shfl_xor(v, 4); v += __shfl_xor(v, 8);
    return v;
}
__device__ __forceinline__ float bcast(float v, int l) {
    return __int_as_float(__builtin_amdgcn_readlane(__float_as_int(v), l));
}
__device__ __forceinline__ float artanh_clip(float n) {
    n = fminf(n, MAXNORM);
    return 0.5f * (log1pf(n) - log1pf(-n));
}
__device__ __forceinline__ float acosh_ref(float z) {
    z = fmaxf(z, 1.0f + EPS1);
    return logf(z + sqrtf(z * z - 1.0f));
}

// ---------------- rank loss ----------------
// 16 lanes per row (lane sub=0..15 holds dims 4*sub..4*sub+3 as float4).
// 4 rows per wave, grid-stride over B rows.
__global__ __launch_bounds__(256) void rank_kernel(
        const float* __restrict__ emb, const int* __restrict__ tri,
        float* __restrict__ part) {
    const int lane    = threadIdx.x & 63;
    const int sub     = lane & 15;
    const int quarter = lane >> 4;
    const int gwave   = (blockIdx.x * blockDim.x + threadIdx.x) >> 6;
    const int stride  = RANK_BLOCKS * 4 * 4;   // waves * quarters
    float acc = 0.f;
    for (int row = gwave * 4 + quarter; row < BROWS; row += stride) {
        const int* t = tri + (long)row * 10;
        const int ui = t[0];
        const int pi = t[1];
        const float4 u4 = *reinterpret_cast<const float4*>(emb + (long)ui * 64 + sub * 4);
        const float4 p4 = *reinterpret_cast<const float4*>(emb + (long)pi * 64 + sub * 4);
        float4 n4[NUM_NEG];
        #pragma unroll
        for (int k = 0; k < NUM_NEG; ++k) {
            const int nix = t[2 + k];
            n4[k] = *reinterpret_cast<const float4*>(emb + (long)nix * 64 + sub * 4);
        }
        // lorentz inner = sum_{d>=1} x_d y_d - x0 y0 = full_dot - 2*x0*y0
        float dp = u4.x * p4.x + u4.y * p4.y + u4.z * p4.z + u4.w * p4.w;
        if (sub == 0) dp -= 2.f * u4.x * p4.x;
        dp = qredsum(dp);
        const float dpos = acosh_ref(-dp);
        const float ps = dpos * dpos;
        const float u0 = __shfl(u4.x, lane & 48);   // quarter-base lane's dim0
        const float alpha = acosh_ref(u0);
        float rs = 0.f;
        #pragma unroll
        for (int k = 0; k < NUM_NEG; ++k) {
            float dn = u4.x * n4[k].x + u4.y * n4[k].y + u4.z * n4[k].z + u4.w * n4[k].w;
            if (sub == 0) dn -= 2.f * u4.x * n4[k].x;
            dn = qredsum(dn);
            const float dneg = acosh_ref(-dn);
            rs += fmaxf((ps - dneg * dneg + MARGIN2) * alpha, 0.f);
        }
        if (sub == 0) acc += rs;     // rs is quarter-uniform; count once
    }
    __shared__ float red[4];
    const float w = wredsum(acc);
    if ((threadIdx.x & 63) == 0) red[threadIdx.x >> 6] = w;
    __syncthreads();
    if (threadIdx.x == 0) part[blockIdx.x] = red[0] + red[1] + red[2] + red[3];
}

// ---------------- cls loss ----------------
// One wave per item. lane = dim for vector phases, lane = tag for dist/hinge.
__global__ __launch_bounds__(256) void cls_kernel(
        const float* __restrict__ vtg, const float* __restrict__ etag,
        const float* __restrict__ linw, const float* __restrict__ linb,
        const float* __restrict__ tw, const int* __restrict__ labels,
        float* __restrict__ part) {
    __shared__ float WT[64 * 65];   // W transposed, pitch 65
    __shared__ float BT[64 * 65];   // logmap0(emb_tag) transposed, pitch 65
    __shared__ float b2s[64];       // ||bt_j||^2
    __shared__ float red[4];
    const int tid = threadIdx.x;
    for (int i = tid; i < 4096; i += 256) {
        const int r = i >> 6, d = i & 63;
        WT[d * 65 + r] = linw[i];          // linw[r*64+d]
    }
    {   // bt = ball_logmap0(emb_tag): 4 threads per tag
        const int j = tid >> 2, p = tid & 3;
        float e[16];
        float s2 = 0.f;
        #pragma unroll
        for (int m = 0; m < 16; ++m) { e[m] = etag[j * 64 + p * 16 + m]; s2 += e[m] * e[m]; }
        s2 += __shfl_xor(s2, 1); s2 += __shfl_xor(s2, 2);
        const float n = sqrtf(fmaxf(s2, 1e-15f));
        const float sc = artanh_clip(n) / n;
        #pragma unroll
        for (int m = 0; m < 16; ++m) BT[(p * 16 + m) * 65 + j] = sc * e[m];
        if (p == 0) b2s[j] = sc * sc * s2;
    }
    __syncthreads();
    const int lane = tid & 63, wid = tid >> 6;
    const float bias = linb[lane];
    const float y2b = wredsum(bias * bias);
    const float twl = tw[lane];
    const float b2l = b2s[lane];
    const int gw = blockIdx.x * 4 + wid, nw = CLS_BLOCKS * 4;
    float acc = 0.f;
    for (int i = gw; i < NUM_ITEMS_C; i += nw) {
        float x = vtg[(long)i * 64 + lane];
        float x2 = wredsum(x * x);
        float xn = sqrtf(fmaxf(x2, 1e-15f));
        if (xn > MAXNORM) {                       // ball_projx (wave-uniform branch)
            x *= MAXNORM / xn;
            x2 = wredsum(x * x);
            xn = sqrtf(fmaxf(x2, 1e-15f));
        }
        // mobius_matvec: mx[r] = sum_d x_d W[r][d]  (lane = r)
        float mx = 0.f;
        #pragma unroll
        for (int d = 0; d < 64; ++d) mx = fmaf(bcast(x, d), WT[d * 65 + lane], mx);
        const float mn2 = wredsum(mx * mx);
        const float mn = sqrtf(fmaxf(mn2, 1e-15f));
        const float g = tanhf(mn / xn * artanh_clip(xn));
        const float h1 = g / mn * mx;
        const float x2h = wredsum(h1 * h1);
        const float xy = wredsum(h1 * bias);
        const float A = 1.f + 2.f * xy + y2b;
        const float Bc = 1.f - x2h;
        const float den = fmaxf(1.f + 2.f * xy + x2h * y2b, 1e-15f);
        float hh = (A * h1 + Bc * bias) / den;
        float h2 = wredsum(hh * hh);
        float hn = sqrtf(fmaxf(h2, 1e-15f));
        if (hn > MAXNORM) {                       // ball_projx
            hh *= MAXNORM / hn;
            h2 = wredsum(hh * hh);
            hn = sqrtf(fmaxf(h2, 1e-15f));
        }
        const float a = artanh_clip(hn) / hn * hh;  // ball_logmap0
        const float a2 = wredsum(a * a);
        // dist to tag j  (lane = j)
        float dot = 0.f;
        #pragma unroll
        for (int d = 0; d < 64; ++d) dot = fmaf(bcast(a, d), BT[d * 65 + lane], dot);
        const float dist = sqrtf(fmaxf(a2 + b2l - 2.f * dot, 1e-12f));
        const float logp = logf(dist) - twl;
        float s = 0.f;
        #pragma unroll
        for (int k = 0; k < 64; ++k) s += fmaxf(logp - bcast(logp, k) + MARGIN1, 0.f);
        const float c = (labels[(long)i * 64 + lane] > 0) ? s : 0.f;
        acc += wredsum(c);
    }
    if (lane == 0) red[wid] = acc;
    __syncthreads();
    if (tid == 0) part[blockIdx.x] = red[0] + red[1] + red[2] + red[3];
}

// ---------------- cl loss ----------------
// One wave per implication pair, lane = tag j.
__global__ __launch_bounds__(256) void cl_kernel(
        const float* __restrict__ etag, const int* __restrict__ imp,
        float* __restrict__ part) {
    __shared__ float TT[64 * 65];   // emb_tag transposed, pitch 65
    __shared__ float y2s[64];       // ||tag_j||^2
    __shared__ float red[4];
    const int tid = threadIdx.x;
    {
        const int j = tid >> 2, p = tid & 3;
        float s2 = 0.f;
        #pragma unroll
        for (int m = 0; m < 16; ++m) {
            const float e = etag[j * 64 + p * 16 + m];
            s2 += e * e;
            TT[(p * 16 + m) * 65 + j] = e;
        }
        s2 += __shfl_xor(s2, 1); s2 += __shfl_xor(s2, 2);
        if (p == 0) y2s[j] = s2;
    }
    __syncthreads();
    const int lane = tid & 63, wid = tid >> 6;
    const float y2l = y2s[lane];
    const int gw = blockIdx.x * 4 + wid, nw = CL_BLOCKS * 4;
    float acc = 0.f;
    for (int pI = gw; pI < M_IMP_C; pI += nw) {
        const int ai = imp[pI * 2];
        const int bi = imp[pI * 2 + 1];
        const float x2 = y2s[ai];
        float c = 0.f;
        #pragma unroll
        for (int d = 0; d < 64; ++d) c = fmaf(TT[d * 65 + ai], TT[d * 65 + lane], c);
        // mobius_add(-q, y):  ||num||^2 = A^2 x2 - 2 A Bc c + Bc^2 y2
        const float A = 1.f - 2.f * c + y2l;
        const float Bc = 1.f - x2;
        const float nn = A * A * x2 - 2.f * A * Bc * c + Bc * Bc * y2l;
        const float den = fmaxf(1.f - 2.f * c + x2 * y2l, 1e-15f);
        float n = sqrtf(fmaxf(nn / (den * den), 1e-15f));
        n = fminf(n, MAXNORM);
        const float dd = log1pf(n) - log1pf(-n);    // 2*artanh(n)
        float dist = dd * dd;
        if (lane == ai) dist = 0.f;                 // self-distance: ref < 1e-9 -> masked
        const float logit = (dist > 1e-9f) ? (-dist / TAU) : -1e30f;
        const float dp = bcast(dist, bi);           // dist_pos = dist to tag b
        const float lp = bcast(logit, bi);
        const float m = wredmax(logit);
        const float se = wredsum(expf(logit - m)) + expf(lp - m);
        acc += m + logf(se) + dp / TAU;
    }
    if (lane == 0) red[wid] = acc;
    __syncthreads();
    if (tid == 0) part[blockIdx.x] = red[0] + red[1] + red[2] + red[3];
}

// ---------------- final reduction ----------------
__global__ __launch_bounds__(256) void final_reduce(
        const float* __restrict__ parts, int n, float* __restrict__ out) {
    __shared__ double red[256];
    double s = 0.0;
    for (int i = threadIdx.x; i < n; i += 256) s += (double)parts[i];
    red[threadIdx.x] = s;
    __syncthreads();
    for (int off = 128; off > 0; off >>= 1) {
        if (threadIdx.x < off) red[threadIdx.x] += red[threadIdx.x + off];
        __syncthreads();
    }
    if (threadIdx.x == 0) out[0] = (float)red[0];
}

} // namespace

extern "C" void kernel_launch(void* const* d_in, const int* in_sizes, int n_in,
                              void* d_out, int out_size, void* d_ws, size_t ws_size,
                              hipStream_t stream) {
    const float* emb    = (const float*)d_in[0];
    const float* vtg    = (const float*)d_in[1];
    const float* etag   = (const float*)d_in[2];
    const float* linw   = (const float*)d_in[3];
    const float* linb   = (const float*)d_in[4];
    const float* tw     = (const float*)d_in[5];
    const int*   tri    = (const int*)d_in[6];
    const int*   labels = (const int*)d_in[7];
    const int*   imp    = (const int*)d_in[8];
    float* parts = (float*)d_ws;

    rank_kernel<<<RANK_BLOCKS, 256, 0, stream>>>(emb, tri, parts);
    cls_kernel<<<CLS_BLOCKS, 256, 0, stream>>>(vtg, etag, linw, linb, tw, labels,
                                               parts + RANK_BLOCKS);
    cl_kernel<<<CL_BLOCKS, 256, 0, stream>>>(etag, imp,
                                             parts + RANK_BLOCKS + CLS_BLOCKS);
    final_reduce<<<1, 256, 0, stream>>>(parts, NPART, (float*)d_out);
}

// Round 3
// 91.526 us; speedup vs baseline: 1.4966x; 1.4966x over previous
//
#include <hip/hip_runtime.h>
#include <math.h>

namespace {

constexpr int NUM_NEG   = 8;
constexpr int BROWS     = 262144;
constexpr int NUM_ITEMS_C = 20000;
constexpr int M_IMP_C   = 2000;
constexpr float MARGIN1 = 0.1f;
constexpr float MARGIN2 = 0.1f;
constexpr float TAU     = 0.2f;
constexpr float EPS1    = 1e-7f;
constexpr float MAXNORM = 1.0f - 1e-5f;

// block-range dispatch: [cls | cl | rank] — longest-per-block work first
constexpr int CLS_BLOCKS  = 512;
constexpr int CL_BLOCKS   = 64;
constexpr int RANK_BLOCKS = 2048;
constexpr int NBLK = CLS_BLOCKS + CL_BLOCKS + RANK_BLOCKS;

__device__ __forceinline__ float wredsum(float v) {
    v += __shfl_xor(v, 1);  v += __shfl_xor(v, 2);  v += __shfl_xor(v, 4);
    v += __shfl_xor(v, 8);  v += __shfl_xor(v, 16); v += __shfl_xor(v, 32);
    return v;
}
__device__ __forceinline__ float wredmax(float v) {
    v = fmaxf(v, __shfl_xor(v, 1));  v = fmaxf(v, __shfl_xor(v, 2));
    v = fmaxf(v, __shfl_xor(v, 4));  v = fmaxf(v, __shfl_xor(v, 8));
    v = fmaxf(v, __shfl_xor(v, 16)); v = fmaxf(v, __shfl_xor(v, 32));
    return v;
}
__device__ __forceinline__ float qredsum(float v) {
    v += __shfl_xor(v, 1); v += __shfl_xor(v, 2);
    v += __shfl_xor(v, 4); v += __shfl_xor(v, 8);
    return v;
}
__device__ __forceinline__ float bcast(float v, int l) {
    return __int_as_float(__builtin_amdgcn_readlane(__float_as_int(v), l));
}
// fast-math primitives: v_log/v_exp/v_sqrt/v_rcp are ~1 ulp; error budget is ~2% rel.
__device__ __forceinline__ float fsq(float x)  { return __builtin_amdgcn_sqrtf(x); }
__device__ __forceinline__ float frc(float x)  { return __builtin_amdgcn_rcpf(x); }
__device__ __forceinline__ float artanh_fast(float n) {
    n = fminf(n, MAXNORM);
    return 0.5f * __logf((1.f + n) * frc(1.f - n));
}
__device__ __forceinline__ float acosh_fast(float z) {
    z = fmaxf(z, 1.0f + EPS1);
    return __logf(z + fsq(fmaf(z, z, -1.0f)));
}
__device__ __forceinline__ float tanh_fast(float x) {   // x >= 0, moderate
    const float t = __expf(2.f * x);
    return (t - 1.f) * frc(t + 1.f);
}

__global__ __launch_bounds__(256) void fused_kernel(
        const float* __restrict__ emb,  const int* __restrict__ tri,
        const float* __restrict__ vtg,  const float* __restrict__ etag,
        const float* __restrict__ linw, const float* __restrict__ linb,
        const float* __restrict__ tw,   const int* __restrict__ labels,
        const int* __restrict__ imp,    float* __restrict__ part) {
    __shared__ float SA[64 * 65];   // WT (cls) / TT (cl), pitch 65 (conflict-free both ways)
    __shared__ float SB[64 * 65];   // BT (cls)
    __shared__ float s64[64];       // ||bt||^2 (cls) / ||tag||^2 (cl)
    __shared__ float red4[4];
    const int tid  = threadIdx.x;
    const int lane = tid & 63, wid = tid >> 6;
    const int b    = blockIdx.x;
    float wsum = 0.f;               // wave-uniform partial at end of each branch

    if (b < CLS_BLOCKS) {
        // ---------------- cls loss ----------------
        for (int i = tid; i < 4096; i += 256) {
            const int r = i >> 6, d = i & 63;
            SA[d * 65 + r] = linw[i];                  // W transposed
        }
        {   // bt = ball_logmap0(emb_tag), 4 threads per tag
            const int j = tid >> 2, p = tid & 3;
            float e[16]; float s2 = 0.f;
            #pragma unroll
            for (int m = 0; m < 16; ++m) { e[m] = etag[j * 64 + p * 16 + m]; s2 += e[m] * e[m]; }
            s2 += __shfl_xor(s2, 1); s2 += __shfl_xor(s2, 2);
            const float n  = fsq(fmaxf(s2, 1e-15f));
            const float sc = artanh_fast(n) * frc(n);
            #pragma unroll
            for (int m = 0; m < 16; ++m) SB[(p * 16 + m) * 65 + j] = sc * e[m];
            if (p == 0) s64[j] = sc * sc * s2;
        }
        __syncthreads();
        const float bias = linb[lane];
        const float y2b  = wredsum(bias * bias);
        const float twl  = tw[lane];
        const float b2l  = s64[lane];
        const int gw = b * 4 + wid, nw = CLS_BLOCKS * 4;
        float acc = 0.f;
        for (int i = gw; i < NUM_ITEMS_C; i += nw) {
            float x  = vtg[(long)i * 64 + lane];
            float x2 = wredsum(x * x);
            float xn = fsq(fmaxf(x2, 1e-15f));
            if (xn > MAXNORM) {                        // ball_projx (wave-uniform)
                x *= MAXNORM * frc(xn);
                x2 = wredsum(x * x);
                xn = fsq(fmaxf(x2, 1e-15f));
            }
            float mx = 0.f;
            #pragma unroll
            for (int d = 0; d < 64; ++d) mx = fmaf(bcast(x, d), SA[d * 65 + lane], mx);
            const float mn  = fsq(fmaxf(wredsum(mx * mx), 1e-15f));
            const float g   = tanh_fast(mn * frc(xn) * artanh_fast(xn));
            const float h1  = g * frc(mn) * mx;
            const float x2h = wredsum(h1 * h1);
            const float xy  = wredsum(h1 * bias);
            const float A   = 1.f + 2.f * xy + y2b;
            const float Bc  = 1.f - x2h;
            const float den = fmaxf(1.f + 2.f * xy + x2h * y2b, 1e-15f);
            float hh = (A * h1 + Bc * bias) * frc(den);
            float h2 = wredsum(hh * hh);
            float hn = fsq(fmaxf(h2, 1e-15f));
            if (hn > MAXNORM) {                        // ball_projx
                hh *= MAXNORM * frc(hn);
                h2 = wredsum(hh * hh);
                hn = fsq(fmaxf(h2, 1e-15f));
            }
            const float a  = artanh_fast(hn) * frc(hn) * hh;   // ball_logmap0
            const float a2 = wredsum(a * a);
            float dot = 0.f;
            #pragma unroll
            for (int d = 0; d < 64; ++d) dot = fmaf(bcast(a, d), SB[d * 65 + lane], dot);
            const float dist = fsq(fmaxf(a2 + b2l - 2.f * dot, 1e-12f));
            const float logp = __logf(dist) - twl;
            float s = 0.f;
            #pragma unroll
            for (int k = 0; k < 64; ++k) s += fmaxf(logp - bcast(logp, k) + MARGIN1, 0.f);
            const float c = (labels[(long)i * 64 + lane] > 0) ? s : 0.f;
            acc += wredsum(c);
        }
        wsum = acc;
    } else if (b < CLS_BLOCKS + CL_BLOCKS) {
        // ---------------- cl loss ----------------
        const int cb = b - CLS_BLOCKS;
        {
            const int j = tid >> 2, p = tid & 3;
            float s2 = 0.f;
            #pragma unroll
            for (int m = 0; m < 16; ++m) {
                const float e = etag[j * 64 + p * 16 + m];
                s2 += e * e;
                SA[(p * 16 + m) * 65 + j] = e;
            }
            s2 += __shfl_xor(s2, 1); s2 += __shfl_xor(s2, 2);
            if (p == 0) s64[j] = s2;
        }
        __syncthreads();
        const float y2l = s64[lane];
        const int gw = cb * 4 + wid, nw = CL_BLOCKS * 4;
        float acc = 0.f;
        for (int pI = gw; pI < M_IMP_C; pI += nw) {
            const int ai = imp[pI * 2];
            const int bi = imp[pI * 2 + 1];
            const float x2 = s64[ai];
            float c = 0.f;
            #pragma unroll
            for (int d = 0; d < 64; ++d) c = fmaf(SA[d * 65 + ai], SA[d * 65 + lane], c);
            // mobius_add(-q, y): ||num||^2 = A^2 x2 - 2 A Bc c + Bc^2 y2
            const float A   = 1.f - 2.f * c + y2l;
            const float Bc  = 1.f - x2;
            const float nn  = A * A * x2 - 2.f * A * Bc * c + Bc * Bc * y2l;
            const float den = fmaxf(1.f - 2.f * c + x2 * y2l, 1e-15f);
            float n = fsq(fmaxf(nn * frc(den * den), 1e-15f));
            n = fminf(n, MAXNORM);
            const float dd = __logf((1.f + n) * frc(1.f - n));   // 2*artanh(n)
            float dist = dd * dd;
            if (lane == ai) dist = 0.f;            // self-distance: ref < 1e-9 -> masked
            const float logit = (dist > 1e-9f) ? (-dist * (1.f / TAU)) : -1e30f;
            const float dp = bcast(dist, bi);
            const float lp = bcast(logit, bi);
            const float m  = wredmax(logit);
            const float se = wredsum(__expf(logit - m)) + __expf(lp - m);
            acc += m + __logf(se) + dp * (1.f / TAU);
        }
        wsum = acc;
    } else {
        // ---------------- rank loss ----------------
        const int rb = b - CLS_BLOCKS - CL_BLOCKS;
        const int sub = lane & 15, quarter = lane >> 4;
        const int gwave = rb * 4 + wid;
        float acc = 0.f;
        for (int row = gwave * 4 + quarter; row < BROWS; row += RANK_BLOCKS * 16) {
            const int* t = tri + (long)row * 10;
            const int2 t01 = *reinterpret_cast<const int2*>(t);
            const int2 t23 = *reinterpret_cast<const int2*>(t + 2);
            const int2 t45 = *reinterpret_cast<const int2*>(t + 4);
            const int2 t67 = *reinterpret_cast<const int2*>(t + 6);
            const int2 t89 = *reinterpret_cast<const int2*>(t + 8);
            const int nidx[NUM_NEG] = {t23.x, t23.y, t45.x, t45.y,
                                       t67.x, t67.y, t89.x, t89.y};
            const float4 u4 = *reinterpret_cast<const float4*>(emb + (long)t01.x * 64 + sub * 4);
            const float4 p4 = *reinterpret_cast<const float4*>(emb + (long)t01.y * 64 + sub * 4);
            float4 n4[NUM_NEG];
            #pragma unroll
            for (int k = 0; k < NUM_NEG; ++k)
                n4[k] = *reinterpret_cast<const float4*>(emb + (long)nidx[k] * 64 + sub * 4);
            // lorentz inner = full_dot - 2*x0*y0
            float dp = u4.x * p4.x + u4.y * p4.y + u4.z * p4.z + u4.w * p4.w;
            if (sub == 0) dp -= 2.f * u4.x * p4.x;
            dp = qredsum(dp);
            const float dpos = acosh_fast(-dp);
            const float ps = dpos * dpos;
            const float u0 = __shfl(u4.x, lane & 48);
            const float alpha = acosh_fast(u0);
            float rs = 0.f;
            #pragma unroll
            for (int k = 0; k < NUM_NEG; ++k) {
                float dn = u4.x * n4[k].x + u4.y * n4[k].y + u4.z * n4[k].z + u4.w * n4[k].w;
                if (sub == 0) dn -= 2.f * u4.x * n4[k].x;
                dn = qredsum(dn);
                const float dneg = acosh_fast(-dn);
                rs += fmaxf((ps - dneg * dneg + MARGIN2) * alpha, 0.f);
            }
            if (sub == 0) acc += rs;               // quarter-uniform; count once
        }
        wsum = wredsum(acc);
    }

    if (lane == 0) red4[wid] = wsum;
    __syncthreads();
    if (tid == 0) part[b] = red4[0] + red4[1] + red4[2] + red4[3];
}

__global__ __launch_bounds__(256) void final_reduce(
        const float* __restrict__ parts, int n, float* __restrict__ out) {
    __shared__ double red[256];
    double s = 0.0;
    for (int i = threadIdx.x; i < n; i += 256) s += (double)parts[i];
    red[threadIdx.x] = s;
    __syncthreads();
    for (int off = 128; off > 0; off >>= 1) {
        if (threadIdx.x < off) red[threadIdx.x] += red[threadIdx.x + off];
        __syncthreads();
    }
    if (threadIdx.x == 0) out[0] = (float)red[0];
}

} // namespace

extern "C" void kernel_launch(void* const* d_in, const int* in_sizes, int n_in,
                              void* d_out, int out_size, void* d_ws, size_t ws_size,
                              hipStream_t stream) {
    const float* emb    = (const float*)d_in[0];
    const float* vtg    = (const float*)d_in[1];
    const float* etag   = (const float*)d_in[2];
    const float* linw   = (const float*)d_in[3];
    const float* linb   = (const float*)d_in[4];
    const float* tw     = (const float*)d_in[5];
    const int*   tri    = (const int*)d_in[6];
    const int*   labels = (const int*)d_in[7];
    const int*   imp    = (const int*)d_in[8];
    float* parts = (float*)d_ws;

    fused_kernel<<<NBLK, 256, 0, stream>>>(emb, tri, vtg, etag, linw, linb,
                                           tw, labels, imp, parts);
    final_reduce<<<1, 256, 0, stream>>>(parts, NBLK, (float*)d_out);
}